// Round 16
// baseline (200.383 us; speedup 1.0000x reference)
//
#include <hip/hip_runtime.h>

typedef __attribute__((ext_vector_type(8))) __bf16 bf16x8;
typedef __attribute__((ext_vector_type(4))) float f32x4;
typedef unsigned short u16;
typedef unsigned int u32;

#define MFMA16(a, b, c) __builtin_amdgcn_mfma_f32_16x16x32_bf16((a), (b), (c), 0, 0, 0)

__device__ __forceinline__ u16 f2bf(float f) {
  return (u16)((__float_as_uint(f) + 0x8000u) >> 16);
}

// dims
#define BDIM 2
#define SDIM 2048
#define EDIM 1024
#define HDIM 16
#define HD 64
#define MDIM (BDIM * SDIM)  // 4096

// q pre-scale: 0.125 * log2(e), folded into q at the QKV-GEMM epilogue
#define SC_C1 0.1803368801111355f

typedef __attribute__((address_space(3))) void lds_void;
typedef __attribute__((address_space(1))) void g_void;

__device__ __forceinline__ void async_lds16(const void* g, void* lds_byte) {
  __builtin_amdgcn_global_load_lds((const g_void*)g, (lds_void*)lds_byte, 16, 0, 0);
}

// ===================== cvt3: three f32 -> bf16 arrays, one launch ==========
__global__ __launch_bounds__(256) void cvt3_kernel(
    const float* __restrict__ s0, u16* __restrict__ d0, int n0,
    const float* __restrict__ s1, u16* __restrict__ d1, int n1,
    const float* __restrict__ s2, u16* __restrict__ d2, int n2) {
  int i = (blockIdx.x * 256 + threadIdx.x) * 8;
  const float* s;
  u16* d;
  if (i < n0) {
    s = s0 + i; d = d0 + i;
  } else if (i < n0 + n1) {
    s = s1 + (i - n0); d = d1 + (i - n0);
  } else if (i < n0 + n1 + n2) {
    s = s2 + (i - n0 - n1); d = d2 + (i - n0 - n1);
  } else {
    return;
  }
  float4 f0 = *(const float4*)(s);
  float4 f1 = *(const float4*)(s + 4);
  union { uint4 u; u16 h[8]; } o;
  o.h[0] = f2bf(f0.x); o.h[1] = f2bf(f0.y); o.h[2] = f2bf(f0.z); o.h[3] = f2bf(f0.w);
  o.h[4] = f2bf(f1.x); o.h[5] = f2bf(f1.y); o.h[6] = f2bf(f1.z); o.h[7] = f2bf(f1.w);
  *(uint4*)(d) = o.u;
}

// ===================== GEMM1: QKV projection (128x128 tile, BK=64) ====
// out: q bf16 [B][H][S][HD] PRE-SCALED by SC_C1; k bf16 [B][H][S][HD];
//      v bf16 TRANSPOSED [B][H][HD][S]
// Epilogue: r10 original segment-coalesced stores (r13/r15 A/B showed the
// epilogue form is a don't-care within the tail's +-4us noise band).
__global__ __launch_bounds__(256) void gemm_qkv_kernel(
    const u16* __restrict__ X, const u16* __restrict__ W,
    const float* __restrict__ bias, u16* __restrict__ qb,
    u16* __restrict__ kb, u16* __restrict__ vtb) {
  __shared__ __align__(16) u16 As[128 * 64];
  __shared__ __align__(16) u16 Bs[128 * 64];
  const int m0 = blockIdx.x * 128, n0 = blockIdx.y * 128;
  const bool isV = (n0 >= 2 * EDIM);
  const int t = threadIdx.x;
  const int l = t & 63;
  const int quad = l >> 4, col = l & 15;
  const int wid = t >> 6;
  const int mh = wid & 1, nh = wid >> 1;
  const int wofs = (t & 192) << 4;  // wave_id * 1024 bytes
  f32x4 acc[4][4] = {};
  const u16* Ab = X + (size_t)m0 * EDIM;
  const u16* Bb = W + (size_t)n0 * EDIM;
  char* AsB = (char*)As;
  char* BsB = (char*)Bs;

  for (int k0 = 0; k0 < EDIM; k0 += 64) {
    __syncthreads();
#pragma unroll
    for (int p = 0; p < 4; p++) {
      int idx = p * 256 + t;       // 0..1023
      int row = idx >> 3;          // 0..127
      int gch = (idx & 7) ^ (row & 7);
      async_lds16(Ab + (size_t)row * EDIM + k0 + gch * 8, AsB + p * 4096 + wofs);
      async_lds16(Bb + (size_t)row * EDIM + k0 + gch * 8, BsB + p * 4096 + wofs);
    }
    __syncthreads();
#pragma unroll
    for (int kk = 0; kk < 2; kk++) {
      bf16x8 af[4], bfr[4];
#pragma unroll
      for (int i = 0; i < 4; i++) {
        int ra = 64 * mh + 16 * i + col;
        af[i] = *(const bf16x8*)&As[ra * 64 + (((kk * 4 + quad) ^ (ra & 7)) * 8)];
        int rb = 64 * nh + 16 * i + col;
        bfr[i] = *(const bf16x8*)&Bs[rb * 64 + (((kk * 4 + quad) ^ (rb & 7)) * 8)];
      }
      if (isV) {
#pragma unroll
        for (int i = 0; i < 4; i++)
#pragma unroll
          for (int j = 0; j < 4; j++)
            acc[i][j] = MFMA16(bfr[i], af[j], acc[i][j]);  // rows = W features
      } else {
#pragma unroll
        for (int i = 0; i < 4; i++)
#pragma unroll
          for (int j = 0; j < 4; j++)
            acc[i][j] = MFMA16(af[i], bfr[j], acc[i][j]);  // rows = tokens
      }
    }
  }

  if (isV) {
#pragma unroll
    for (int i = 0; i < 4; i++)
#pragma unroll
      for (int j = 0; j < 4; j++)
#pragma unroll
        for (int r = 0; r < 4; r++) {
          int n = n0 + 64 * nh + 16 * i + quad * 4 + r;  // feature (2048..3071)
          int m = m0 + 64 * mh + 16 * j + col;           // token
          float val = acc[i][j][r] + bias[n];
          int e = n & 1023;
          int hh = e >> 6, d = e & 63;
          int bb = m >> 11, s = m & 2047;
          vtb[(((size_t)(bb * HDIM + hh)) * HD + d) * SDIM + s] = f2bf(val);
        }
  } else {
    const float qscale = (n0 < EDIM) ? SC_C1 : 1.0f;  // block-uniform
#pragma unroll
    for (int i = 0; i < 4; i++)
#pragma unroll
      for (int j = 0; j < 4; j++)
#pragma unroll
        for (int r = 0; r < 4; r++) {
          int m = m0 + 64 * mh + 16 * i + quad * 4 + r;
          int n = n0 + 64 * nh + 16 * j + col;
          float val = (acc[i][j][r] + bias[n]) * qscale;
          int which = n >> 10, e = n & 1023;
          int hh = e >> 6, d = e & 63;
          int bb = m >> 11, s = m & 2047;
          u16* dst = (which == 0) ? qb : kb;
          dst[(((size_t)(bb * HDIM + hh)) * SDIM + s) * HD + d] = f2bf(val);
        }
  }
}

// ===================== Attention: 8-wave, ping-pong + zero-C QK^T ==========
// r14 structure (69.5-69.9 us) with the last per-iter VALU block removed:
// the 16x v_mov nxt[ct]={0} init is replaced by zero-C on the first MFMA of
// each score chain (D != C is legal; pattern correctness-proven in r8/r9).
// qkt restructured ct-outer: each chain = {MFMA(aq0,kf0,Z), MFMA(aq1,kf1,acc)}.
__global__ __launch_bounds__(512, 4) void attn_kernel(
    const u16* __restrict__ qg, const u16* __restrict__ kg,
    const u16* __restrict__ vtg, u16* __restrict__ ctx) {
  __shared__ __align__(16) u16 KB[2][64 * 64];
  __shared__ __align__(16) u16 VB[3][64 * 64];
  __shared__ __align__(16) u16 Ps[128 * 68];

  const int bh = blockIdx.x;  // b*16 + h
  const int q0 = blockIdx.y * 128;
  const int t = threadIdx.x;
  const int wid = t >> 6, l = t & 63;
  const int quad = l >> 4, col = l & 15;
  const size_t base = (size_t)bh * SDIM * HD;

  // Q fragments (A-operand layout): wave wid owns rows q0+16*wid .. +15
  bf16x8 aq[2];
  {
    const u16* qp = qg + base + (size_t)(q0 + 16 * wid + col) * HD + quad * 8;
    aq[0] = *(const bf16x8*)(qp);
    aq[1] = *(const bf16x8*)(qp + 32);
  }
  const int qw0 = q0 + 16 * wid;              // wave's first q row
  const int qrow = qw0 + quad * 4;            // + r

  // staging: thread t covers row = t>>3 (0..63), chunk g = (t&7)^(row&7);
  // LDS linear byte = t*16 (wave-uniform base wid*1024 + lane*16).
  const int srow = t >> 3;
  const int g = (t & 7) ^ (srow & 7);
  const u16* kptr = kg + base + (size_t)srow * HD + g * 8;
  const u16* vptr = vtg + base + (size_t)srow * SDIM + g * 8;
  const int wofs = wid << 10;  // wave_id * 1024 bytes (uniform per wave)

  auto stageK = [&](int kt, int buf) {
    async_lds16(kptr + (size_t)(kt * 64) * HD, (char*)KB[buf] + wofs);
  };
  auto stageV = [&](int kt, int buf) {
    async_lds16(vptr + kt * 64, (char*)VB[buf] + wofs);
  };

  const f32x4 Z = {};  // loop-invariant zero C for first MFMA of each chain

  // QK^T: per ct, chain = zero-C MFMA (aq[0]) then accumulate (aq[1]).
  auto qkt = [&](const u16* Kt, f32x4* sco) {
#pragma unroll
    for (int ct = 0; ct < 4; ct++) {
      int r = 16 * ct + col;
      int r7 = r & 7;
      bf16x8 k0f = *(const bf16x8*)&Kt[r * 64 + ((quad ^ r7) * 8)];
      bf16x8 k1f = *(const bf16x8*)&Kt[r * 64 + (((4 + quad) ^ r7) * 8)];
      f32x4 a0 = MFMA16(aq[0], k0f, Z);
      sco[ct] = MFMA16(aq[1], k1f, a0);
    }
  };

  float psum[4] = {};
  f32x4 oacc[4] = {};
  f32x4 scA[4], scB[4];

  const int NT = SDIM / 64;  // 32
  stageK(0, 0);
  stageV(0, 0);
  __syncthreads();
  qkt(KB[0], scA);
  stageK(1, 1);
  stageV(1, 1);

  int vb_n = 2;  // (kt+2)%3 tracker
  int vb_c = 0;  // kt%3 tracker

  // One iteration: barrier; QK^T(t+1) into nxt [MFMA bg]; stage(t+2);
  // softmax(t) on cur [VALU overlaps]; PV(t). No init movs, no cur<-nxt copy.
  auto iter = [&](int kt, f32x4 (&cur)[4], f32x4 (&nxt)[4]) {
    __syncthreads();  // drains DMAs issued last iter: K(t+1), V(t+1)
    if (kt + 1 < NT) {
      qkt(KB[(kt + 1) & 1], nxt);
    }
    if (kt + 2 < NT) {
      stageK(kt + 2, kt & 1);
      stageV(kt + 2, vb_n);
    }
    vb_n = (vb_n == 2) ? 0 : vb_n + 1;

    // softmax(t): p = exp2(s)  (scale folded into q; no max subtraction)
    const int k0 = kt * 64;
    const int pbase = (16 * wid + quad * 4) * 68 + col;
    if (k0 <= qw0 + 15 && k0 + 63 >= qw0 - 16) {
#pragma unroll
      for (int ct = 0; ct < 4; ct++)
#pragma unroll
        for (int r = 0; r < 4; r++) {
          int i = qrow + r, j = k0 + 16 * ct + col;
          float arg = (j <= i && j + 16 >= i) ? -1.0e30f : cur[ct][r];
          float p = __builtin_exp2f(arg);
          psum[r] += p;
          Ps[pbase + r * 68 + 16 * ct] = f2bf(p);
        }
    } else {
#pragma unroll
      for (int ct = 0; ct < 4; ct++)
#pragma unroll
        for (int r = 0; r < 4; r++) {
          float p = __builtin_exp2f(cur[ct][r]);
          psum[r] += p;
          Ps[pbase + r * 68 + 16 * ct] = f2bf(p);
        }
    }

    // PV(t): Ps (wave-private, lgkm-ordered) x V from VB[t%3]
    const u16* Vt = VB[vb_c];
    vb_c = (vb_c == 2) ? 0 : vb_c + 1;
#pragma unroll
    for (int half = 0; half < 2; half++) {
      bf16x8 pa =
          *(const bf16x8*)&Ps[(16 * wid + col) * 68 + half * 32 + quad * 8];
#pragma unroll
      for (int dt = 0; dt < 4; dt++) {
        int vr = 16 * dt + col;
        int phys = (4 * half + quad) ^ (vr & 7);
        bf16x8 vbf = *(const bf16x8*)&Vt[vr * 64 + phys * 8];
        oacc[dt] = MFMA16(pa, vbf, oacc[dt]);
      }
    }
  };

#pragma unroll 1
  for (int kt = 0; kt < NT; kt += 2) {
    iter(kt, scA, scB);
    iter(kt + 1, scB, scA);
  }

  // reduce l across the 16-lane col group (once)
#pragma unroll
  for (int off = 1; off < 16; off <<= 1)
#pragma unroll
    for (int r = 0; r < 4; r++) psum[r] += __shfl_xor(psum[r], off, 64);

  // epilogue: ctx[b][s][h*64+d] = O / l   (bf16)
  const int b = bh >> 4, h = bh & 15;
  float linv[4];
#pragma unroll
  for (int r = 0; r < 4; r++) linv[r] = 1.0f / psum[r];
#pragma unroll
  for (int dt = 0; dt < 4; dt++)
#pragma unroll
    for (int r = 0; r < 4; r++) {
      int qgl = qrow + r;
      int d = 16 * dt + col;
      ctx[((size_t)(b * SDIM + qgl)) * EDIM + h * HD + d] =
          f2bf(oacc[dt][r] * linv[r]);
    }
}

// ===================== GEMM2: output projection (128x64 tile, BK=64) =======
// r10 original epilogue (quad-contiguous 64B store segments); grid 512.
__global__ __launch_bounds__(256) void gemm_out_kernel(
    const u16* __restrict__ A, const u16* __restrict__ W,
    const float* __restrict__ bias, float* __restrict__ out) {
  __shared__ __align__(16) u16 As[128 * 64];
  __shared__ __align__(16) u16 Bs[64 * 64];
  const int m0 = blockIdx.x * 128, n0 = blockIdx.y * 64;
  const int t = threadIdx.x;
  const int l = t & 63;
  const int quad = l >> 4, col = l & 15;
  const int wid = t >> 6;
  const int mh = wid & 1, nh = wid >> 1;
  const int wofs = (t & 192) << 4;
  f32x4 acc[4][2] = {};
  const u16* Ab = A + (size_t)m0 * EDIM;
  const u16* Bb = W + (size_t)n0 * EDIM;
  char* AsB = (char*)As;
  char* BsB = (char*)Bs;

  for (int k0 = 0; k0 < EDIM; k0 += 64) {
    __syncthreads();
#pragma unroll
    for (int p = 0; p < 4; p++) {
      int idx = p * 256 + t;       // 0..1023 -> As rows 0..127
      int row = idx >> 3;
      int gch = (idx & 7) ^ (row & 7);
      async_lds16(Ab + (size_t)row * EDIM + k0 + gch * 8, AsB + p * 4096 + wofs);
    }
#pragma unroll
    for (int p = 0; p < 2; p++) {
      int idx = p * 256 + t;       // 0..511 -> Bs rows 0..63
      int row = idx >> 3;
      int gch = (idx & 7) ^ (row & 7);
      async_lds16(Bb + (size_t)row * EDIM + k0 + gch * 8, BsB + p * 4096 + wofs);
    }
    __syncthreads();
#pragma unroll
    for (int kk = 0; kk < 2; kk++) {
      bf16x8 af[4], bfr[2];
#pragma unroll
      for (int i = 0; i < 4; i++) {
        int ra = 64 * mh + 16 * i + col;
        af[i] = *(const bf16x8*)&As[ra * 64 + (((kk * 4 + quad) ^ (ra & 7)) * 8)];
      }
#pragma unroll
      for (int j = 0; j < 2; j++) {
        int rb = 32 * nh + 16 * j + col;
        bfr[j] = *(const bf16x8*)&Bs[rb * 64 + (((kk * 4 + quad) ^ (rb & 7)) * 8)];
      }
#pragma unroll
      for (int i = 0; i < 4; i++)
#pragma unroll
        for (int j = 0; j < 2; j++)
          acc[i][j] = MFMA16(af[i], bfr[j], acc[i][j]);
    }
  }

#pragma unroll
  for (int i = 0; i < 4; i++)
#pragma unroll
    for (int j = 0; j < 2; j++)
#pragma unroll
      for (int r = 0; r < 4; r++) {
        int m = m0 + 64 * mh + 16 * i + quad * 4 + r;
        int n = n0 + 32 * nh + 16 * j + col;
        out[(size_t)m * EDIM + n] = acc[i][j][r] + bias[n];
      }
}

extern "C" void kernel_launch(void* const* d_in, const int* in_sizes, int n_in,
                              void* d_out, int out_size, void* d_ws,
                              size_t ws_size, hipStream_t stream) {
  const float* x = (const float*)d_in[0];
  const float* in_w = (const float*)d_in[2];
  const float* in_b = (const float*)d_in[3];
  const float* out_w = (const float*)d_in[4];
  const float* out_b = (const float*)d_in[5];
  float* out = (float*)d_out;

  char* ws = (char*)d_ws;
  u16* Xb  = (u16*)ws;                           // 8 MB (reused as ctx)
  u16* ctx = (u16*)ws;                           // alias of Xb
  u16* qb  = (u16*)(ws + (size_t)( 8 << 20));    // 8 MB (pre-scaled q)
  u16* kb  = (u16*)(ws + (size_t)(16 << 20));    // 8 MB
  u16* vtb = (u16*)(ws + (size_t)(24 << 20));    // 8 MB (transposed V)
  u16* Wib = (u16*)(ws + (size_t)(32 << 20));    // 6 MB
  u16* Wob = (u16*)(ws + (size_t)(38 << 20));    // 2 MB

  const int nX = MDIM * EDIM;
  const int nWi = 3 * EDIM * EDIM;
  const int nWo = EDIM * EDIM;
  cvt3_kernel<<<(nX + nWi + nWo) / 8 / 256, 256, 0, stream>>>(
      x, Xb, nX, in_w, Wib, nWi, out_w, Wob, nWo);

  gemm_qkv_kernel<<<dim3(MDIM / 128, 3 * EDIM / 128), 256, 0, stream>>>(
      Xb, Wib, in_b, qb, kb, vtb);
  attn_kernel<<<dim3(BDIM * HDIM, SDIM / 128), 512, 0, stream>>>(qb, kb, vtb, ctx);
  gemm_out_kernel<<<dim3(MDIM / 128, EDIM / 64), 256, 0, stream>>>(
      ctx, Wob, out_b, out);
}

// Round 17
// 197.055 us; speedup vs baseline: 1.0169x; 1.0169x over previous
//
#include <hip/hip_runtime.h>

typedef __attribute__((ext_vector_type(8))) __bf16 bf16x8;
typedef __attribute__((ext_vector_type(4))) float f32x4;
typedef unsigned short u16;
typedef unsigned int u32;

#define MFMA16(a, b, c) __builtin_amdgcn_mfma_f32_16x16x32_bf16((a), (b), (c), 0, 0, 0)

__device__ __forceinline__ u16 f2bf(float f) {
  return (u16)((__float_as_uint(f) + 0x8000u) >> 16);
}

// dims
#define BDIM 2
#define SDIM 2048
#define EDIM 1024
#define HDIM 16
#define HD 64
#define MDIM (BDIM * SDIM)  // 4096

// q pre-scale: 0.125 * log2(e), folded into q at the QKV-GEMM epilogue
#define SC_C1 0.1803368801111355f

typedef __attribute__((address_space(3))) void lds_void;
typedef __attribute__((address_space(1))) void g_void;

__device__ __forceinline__ void async_lds16(const void* g, void* lds_byte) {
  __builtin_amdgcn_global_load_lds((const g_void*)g, (lds_void*)lds_byte, 16, 0, 0);
}

// ===================== cvt3: three f32 -> bf16 arrays, one launch ==========
__global__ __launch_bounds__(256) void cvt3_kernel(
    const float* __restrict__ s0, u16* __restrict__ d0, int n0,
    const float* __restrict__ s1, u16* __restrict__ d1, int n1,
    const float* __restrict__ s2, u16* __restrict__ d2, int n2) {
  int i = (blockIdx.x * 256 + threadIdx.x) * 8;
  const float* s;
  u16* d;
  if (i < n0) {
    s = s0 + i; d = d0 + i;
  } else if (i < n0 + n1) {
    s = s1 + (i - n0); d = d1 + (i - n0);
  } else if (i < n0 + n1 + n2) {
    s = s2 + (i - n0 - n1); d = d2 + (i - n0 - n1);
  } else {
    return;
  }
  float4 f0 = *(const float4*)(s);
  float4 f1 = *(const float4*)(s + 4);
  union { uint4 u; u16 h[8]; } o;
  o.h[0] = f2bf(f0.x); o.h[1] = f2bf(f0.y); o.h[2] = f2bf(f0.z); o.h[3] = f2bf(f0.w);
  o.h[4] = f2bf(f1.x); o.h[5] = f2bf(f1.y); o.h[6] = f2bf(f1.z); o.h[7] = f2bf(f1.w);
  *(uint4*)(d) = o.u;
}

// ===================== GEMM1: QKV projection (128x128 tile, BK=64) ====
// out: q bf16 [B][H][S][HD] PRE-SCALED by SC_C1; k bf16 [B][H][S][HD];
//      v bf16 TRANSPOSED [B][H][HD][S]
// Epilogue: r10 original segment-coalesced stores.
__global__ __launch_bounds__(256) void gemm_qkv_kernel(
    const u16* __restrict__ X, const u16* __restrict__ W,
    const float* __restrict__ bias, u16* __restrict__ qb,
    u16* __restrict__ kb, u16* __restrict__ vtb) {
  __shared__ __align__(16) u16 As[128 * 64];
  __shared__ __align__(16) u16 Bs[128 * 64];
  const int m0 = blockIdx.x * 128, n0 = blockIdx.y * 128;
  const bool isV = (n0 >= 2 * EDIM);
  const int t = threadIdx.x;
  const int l = t & 63;
  const int quad = l >> 4, col = l & 15;
  const int wid = t >> 6;
  const int mh = wid & 1, nh = wid >> 1;
  const int wofs = (t & 192) << 4;  // wave_id * 1024 bytes
  f32x4 acc[4][4] = {};
  const u16* Ab = X + (size_t)m0 * EDIM;
  const u16* Bb = W + (size_t)n0 * EDIM;
  char* AsB = (char*)As;
  char* BsB = (char*)Bs;

  for (int k0 = 0; k0 < EDIM; k0 += 64) {
    __syncthreads();
#pragma unroll
    for (int p = 0; p < 4; p++) {
      int idx = p * 256 + t;       // 0..1023
      int row = idx >> 3;          // 0..127
      int gch = (idx & 7) ^ (row & 7);
      async_lds16(Ab + (size_t)row * EDIM + k0 + gch * 8, AsB + p * 4096 + wofs);
      async_lds16(Bb + (size_t)row * EDIM + k0 + gch * 8, BsB + p * 4096 + wofs);
    }
    __syncthreads();
#pragma unroll
    for (int kk = 0; kk < 2; kk++) {
      bf16x8 af[4], bfr[4];
#pragma unroll
      for (int i = 0; i < 4; i++) {
        int ra = 64 * mh + 16 * i + col;
        af[i] = *(const bf16x8*)&As[ra * 64 + (((kk * 4 + quad) ^ (ra & 7)) * 8)];
        int rb = 64 * nh + 16 * i + col;
        bfr[i] = *(const bf16x8*)&Bs[rb * 64 + (((kk * 4 + quad) ^ (rb & 7)) * 8)];
      }
      if (isV) {
#pragma unroll
        for (int i = 0; i < 4; i++)
#pragma unroll
          for (int j = 0; j < 4; j++)
            acc[i][j] = MFMA16(bfr[i], af[j], acc[i][j]);  // rows = W features
      } else {
#pragma unroll
        for (int i = 0; i < 4; i++)
#pragma unroll
          for (int j = 0; j < 4; j++)
            acc[i][j] = MFMA16(af[i], bfr[j], acc[i][j]);  // rows = tokens
      }
    }
  }

  if (isV) {
#pragma unroll
    for (int i = 0; i < 4; i++)
#pragma unroll
      for (int j = 0; j < 4; j++)
#pragma unroll
        for (int r = 0; r < 4; r++) {
          int n = n0 + 64 * nh + 16 * i + quad * 4 + r;  // feature (2048..3071)
          int m = m0 + 64 * mh + 16 * j + col;           // token
          float val = acc[i][j][r] + bias[n];
          int e = n & 1023;
          int hh = e >> 6, d = e & 63;
          int bb = m >> 11, s = m & 2047;
          vtb[(((size_t)(bb * HDIM + hh)) * HD + d) * SDIM + s] = f2bf(val);
        }
  } else {
    const float qscale = (n0 < EDIM) ? SC_C1 : 1.0f;  // block-uniform
#pragma unroll
    for (int i = 0; i < 4; i++)
#pragma unroll
      for (int j = 0; j < 4; j++)
#pragma unroll
        for (int r = 0; r < 4; r++) {
          int m = m0 + 64 * mh + 16 * i + quad * 4 + r;
          int n = n0 + 64 * nh + 16 * j + col;
          float val = (acc[i][j][r] + bias[n]) * qscale;
          int which = n >> 10, e = n & 1023;
          int hh = e >> 6, d = e & 63;
          int bb = m >> 11, s = m & 2047;
          u16* dst = (which == 0) ? qb : kb;
          dst[(((size_t)(bb * HDIM + hh)) * SDIM + s) * HD + d] = f2bf(val);
        }
  }
}

// ===================== Attention: 8-wave block, r14/r15 winner =============
// Session-best attn (69.5-69.9 us, occ ~35%, VGPR 56, 0 conflicts):
// r0 inner loop scaled to 8 waves (r10) + 2x-unrolled score ping-pong (r14).
// r16's zero-C variant regressed (+1.4 us): ct-outer chains put DEPENDENT
// MFMAs back-to-back (16-cyc result latency exposed), while the half-outer
// form here issues 4 independent MFMAs per half — scheduling freedom beats
// instruction count. Kept half-outer with explicit init movs.
__global__ __launch_bounds__(512, 4) void attn_kernel(
    const u16* __restrict__ qg, const u16* __restrict__ kg,
    const u16* __restrict__ vtg, u16* __restrict__ ctx) {
  __shared__ __align__(16) u16 KB[2][64 * 64];
  __shared__ __align__(16) u16 VB[3][64 * 64];
  __shared__ __align__(16) u16 Ps[128 * 68];

  const int bh = blockIdx.x;  // b*16 + h
  const int q0 = blockIdx.y * 128;
  const int t = threadIdx.x;
  const int wid = t >> 6, l = t & 63;
  const int quad = l >> 4, col = l & 15;
  const size_t base = (size_t)bh * SDIM * HD;

  // Q fragments (A-operand layout): wave wid owns rows q0+16*wid .. +15
  bf16x8 aq[2];
  {
    const u16* qp = qg + base + (size_t)(q0 + 16 * wid + col) * HD + quad * 8;
    aq[0] = *(const bf16x8*)(qp);
    aq[1] = *(const bf16x8*)(qp + 32);
  }
  const int qw0 = q0 + 16 * wid;              // wave's first q row
  const int qrow = qw0 + quad * 4;            // + r

  // staging: thread t covers row = t>>3 (0..63), chunk g = (t&7)^(row&7);
  // LDS linear byte = t*16 (wave-uniform base wid*1024 + lane*16).
  const int srow = t >> 3;
  const int g = (t & 7) ^ (srow & 7);
  const u16* kptr = kg + base + (size_t)srow * HD + g * 8;
  const u16* vptr = vtg + base + (size_t)srow * SDIM + g * 8;
  const int wofs = wid << 10;  // wave_id * 1024 bytes (uniform per wave)

  auto stageK = [&](int kt, int buf) {
    async_lds16(kptr + (size_t)(kt * 64) * HD, (char*)KB[buf] + wofs);
  };
  auto stageV = [&](int kt, int buf) {
    async_lds16(vptr + kt * 64, (char*)VB[buf] + wofs);
  };
  auto qkt = [&](const u16* Kt, f32x4* sco) {
#pragma unroll
    for (int half = 0; half < 2; half++)
#pragma unroll
      for (int ct = 0; ct < 4; ct++) {
        int r = 16 * ct + col;
        int phys = (4 * half + quad) ^ (r & 7);
        bf16x8 bfrag = *(const bf16x8*)&Kt[r * 64 + phys * 8];
        sco[ct] = MFMA16(aq[half], bfrag, sco[ct]);
      }
  };

  float psum[4] = {};
  f32x4 oacc[4] = {};
  f32x4 scA[4] = {}, scB[4];

  const int NT = SDIM / 64;  // 32
  stageK(0, 0);
  stageV(0, 0);
  __syncthreads();
  qkt(KB[0], scA);
  stageK(1, 1);
  stageV(1, 1);

  int vb_n = 2;  // (kt+2)%3 tracker
  int vb_c = 0;  // kt%3 tracker

  // One iteration: barrier; QK^T(t+1) into nxt [MFMA bg]; stage(t+2);
  // softmax(t) on cur [VALU overlaps]; PV(t). No cur<-nxt copy.
  auto iter = [&](int kt, f32x4 (&cur)[4], f32x4 (&nxt)[4]) {
    __syncthreads();  // drains DMAs issued last iter: K(t+1), V(t+1)
    if (kt + 1 < NT) {
#pragma unroll
      for (int ct = 0; ct < 4; ct++) nxt[ct] = f32x4{0.f, 0.f, 0.f, 0.f};
      qkt(KB[(kt + 1) & 1], nxt);
    }
    if (kt + 2 < NT) {
      stageK(kt + 2, kt & 1);
      stageV(kt + 2, vb_n);
    }
    vb_n = (vb_n == 2) ? 0 : vb_n + 1;

    // softmax(t): p = exp2(s)  (scale folded into q; no max subtraction)
    const int k0 = kt * 64;
    const int pbase = (16 * wid + quad * 4) * 68 + col;
    if (k0 <= qw0 + 15 && k0 + 63 >= qw0 - 16) {
#pragma unroll
      for (int ct = 0; ct < 4; ct++)
#pragma unroll
        for (int r = 0; r < 4; r++) {
          int i = qrow + r, j = k0 + 16 * ct + col;
          float arg = (j <= i && j + 16 >= i) ? -1.0e30f : cur[ct][r];
          float p = __builtin_exp2f(arg);
          psum[r] += p;
          Ps[pbase + r * 68 + 16 * ct] = f2bf(p);
        }
    } else {
#pragma unroll
      for (int ct = 0; ct < 4; ct++)
#pragma unroll
        for (int r = 0; r < 4; r++) {
          float p = __builtin_exp2f(cur[ct][r]);
          psum[r] += p;
          Ps[pbase + r * 68 + 16 * ct] = f2bf(p);
        }
    }

    // PV(t): Ps (wave-private, lgkm-ordered) x V from VB[t%3]
    const u16* Vt = VB[vb_c];
    vb_c = (vb_c == 2) ? 0 : vb_c + 1;
#pragma unroll
    for (int half = 0; half < 2; half++) {
      bf16x8 pa =
          *(const bf16x8*)&Ps[(16 * wid + col) * 68 + half * 32 + quad * 8];
#pragma unroll
      for (int dt = 0; dt < 4; dt++) {
        int vr = 16 * dt + col;
        int phys = (4 * half + quad) ^ (vr & 7);
        bf16x8 vbf = *(const bf16x8*)&Vt[vr * 64 + phys * 8];
        oacc[dt] = MFMA16(pa, vbf, oacc[dt]);
      }
    }
  };

#pragma unroll 1
  for (int kt = 0; kt < NT; kt += 2) {
    iter(kt, scA, scB);
    iter(kt + 1, scB, scA);
  }

  // reduce l across the 16-lane col group (once)
#pragma unroll
  for (int off = 1; off < 16; off <<= 1)
#pragma unroll
    for (int r = 0; r < 4; r++) psum[r] += __shfl_xor(psum[r], off, 64);

  // epilogue: ctx[b][s][h*64+d] = O / l   (bf16)
  const int b = bh >> 4, h = bh & 15;
  float linv[4];
#pragma unroll
  for (int r = 0; r < 4; r++) linv[r] = 1.0f / psum[r];
#pragma unroll
  for (int dt = 0; dt < 4; dt++)
#pragma unroll
    for (int r = 0; r < 4; r++) {
      int qgl = qrow + r;
      int d = 16 * dt + col;
      ctx[((size_t)(b * SDIM + qgl)) * EDIM + h * HD + d] =
          f2bf(oacc[dt][r] * linv[r]);
    }
}

// ===================== GEMM2: output projection (128x64 tile, BK=64) =======
// r10 original epilogue (quad-contiguous 64B store segments); grid 512.
__global__ __launch_bounds__(256) void gemm_out_kernel(
    const u16* __restrict__ A, const u16* __restrict__ W,
    const float* __restrict__ bias, float* __restrict__ out) {
  __shared__ __align__(16) u16 As[128 * 64];
  __shared__ __align__(16) u16 Bs[64 * 64];
  const int m0 = blockIdx.x * 128, n0 = blockIdx.y * 64;
  const int t = threadIdx.x;
  const int l = t & 63;
  const int quad = l >> 4, col = l & 15;
  const int wid = t >> 6;
  const int mh = wid & 1, nh = wid >> 1;
  const int wofs = (t & 192) << 4;
  f32x4 acc[4][2] = {};
  const u16* Ab = A + (size_t)m0 * EDIM;
  const u16* Bb = W + (size_t)n0 * EDIM;
  char* AsB = (char*)As;
  char* BsB = (char*)Bs;

  for (int k0 = 0; k0 < EDIM; k0 += 64) {
    __syncthreads();
#pragma unroll
    for (int p = 0; p < 4; p++) {
      int idx = p * 256 + t;       // 0..1023 -> As rows 0..127
      int row = idx >> 3;
      int gch = (idx & 7) ^ (row & 7);
      async_lds16(Ab + (size_t)row * EDIM + k0 + gch * 8, AsB + p * 4096 + wofs);
    }
#pragma unroll
    for (int p = 0; p < 2; p++) {
      int idx = p * 256 + t;       // 0..511 -> Bs rows 0..63
      int row = idx >> 3;
      int gch = (idx & 7) ^ (row & 7);
      async_lds16(Bb + (size_t)row * EDIM + k0 + gch * 8, BsB + p * 4096 + wofs);
    }
    __syncthreads();
#pragma unroll
    for (int kk = 0; kk < 2; kk++) {
      bf16x8 af[4], bfr[2];
#pragma unroll
      for (int i = 0; i < 4; i++) {
        int ra = 64 * mh + 16 * i + col;
        af[i] = *(const bf16x8*)&As[ra * 64 + (((kk * 4 + quad) ^ (ra & 7)) * 8)];
      }
#pragma unroll
      for (int j = 0; j < 2; j++) {
        int rb = 32 * nh + 16 * j + col;
        bfr[j] = *(const bf16x8*)&Bs[rb * 64 + (((kk * 4 + quad) ^ (rb & 7)) * 8)];
      }
#pragma unroll
      for (int i = 0; i < 4; i++)
#pragma unroll
        for (int j = 0; j < 2; j++)
          acc[i][j] = MFMA16(af[i], bfr[j], acc[i][j]);
    }
  }

#pragma unroll
  for (int i = 0; i < 4; i++)
#pragma unroll
    for (int j = 0; j < 2; j++)
#pragma unroll
      for (int r = 0; r < 4; r++) {
        int m = m0 + 64 * mh + 16 * i + quad * 4 + r;
        int n = n0 + 32 * nh + 16 * j + col;
        out[(size_t)m * EDIM + n] = acc[i][j][r] + bias[n];
      }
}

extern "C" void kernel_launch(void* const* d_in, const int* in_sizes, int n_in,
                              void* d_out, int out_size, void* d_ws,
                              size_t ws_size, hipStream_t stream) {
  const float* x = (const float*)d_in[0];
  const float* in_w = (const float*)d_in[2];
  const float* in_b = (const float*)d_in[3];
  const float* out_w = (const float*)d_in[4];
  const float* out_b = (const float*)d_in[5];
  float* out = (float*)d_out;

  char* ws = (char*)d_ws;
  u16* Xb  = (u16*)ws;                           // 8 MB (reused as ctx)
  u16* ctx = (u16*)ws;                           // alias of Xb
  u16* qb  = (u16*)(ws + (size_t)( 8 << 20));    // 8 MB (pre-scaled q)
  u16* kb  = (u16*)(ws + (size_t)(16 << 20));    // 8 MB
  u16* vtb = (u16*)(ws + (size_t)(24 << 20));    // 8 MB (transposed V)
  u16* Wib = (u16*)(ws + (size_t)(32 << 20));    // 6 MB
  u16* Wob = (u16*)(ws + (size_t)(38 << 20));    // 2 MB

  const int nX = MDIM * EDIM;
  const int nWi = 3 * EDIM * EDIM;
  const int nWo = EDIM * EDIM;
  cvt3_kernel<<<(nX + nWi + nWo) / 8 / 256, 256, 0, stream>>>(
      x, Xb, nX, in_w, Wib, nWi, out_w, Wob, nWo);

  gemm_qkv_kernel<<<dim3(MDIM / 128, 3 * EDIM / 128), 256, 0, stream>>>(
      Xb, Wib, in_b, qb, kb, vtb);
  attn_kernel<<<dim3(BDIM * HDIM, SDIM / 128), 512, 0, stream>>>(qb, kb, vtb, ctx);
  gemm_out_kernel<<<dim3(MDIM / 128, EDIM / 64), 256, 0, stream>>>(
      ctx, Wob, out_b, out);
}